// Round 17
// baseline (430.166 us; speedup 1.0000x reference)
//
#include <hip/hip_runtime.h>
#include <math.h>

#define NN 50000
#define NE 800000
#define ET (NE + NN)          // edges + self loops = 850000
#define FIN 128
#define HDIM 256
#define NHEAD 4
#define NCLS 40
#define NEG 0.2f
#define NB_SCAN ((NN + 255) / 256)   // 196
#define NB_CONV 3125                 // NN*FIN/8/256
#define NB_WCONV 192                 // 8*8*3
#define NB_EDGE ((ET + 255) / 256)   // 3322
#define NB_FILL ((ET + 511) / 512)   // 1661 (512-thread blocks)
#define GG ( 8 * 2 * (((NN + 127) / 128 + 7) / 8) )   // 784: 49 row-groups x 8 xcd x 2 colblk

typedef short bf16x8 __attribute__((ext_vector_type(8)));
typedef float f32x4 __attribute__((ext_vector_type(4)));

__device__ __forceinline__ unsigned short f2b(float f) {
    unsigned int u = __float_as_uint(f);
    unsigned int r = (u + 0x7fffu + ((u >> 16) & 1u)) >> 16;
    return (unsigned short)r;
}
__device__ __forceinline__ unsigned int cvtpk(float lo, float hi) {
    unsigned int r;
    asm volatile("v_cvt_pk_bf16_f32 %0, %1, %2" : "=v"(r) : "v"(lo), "v"(hi));
    return r;
}
__device__ __forceinline__ float b2f(unsigned short u) {
    unsigned int x = ((unsigned int)u) << 16;
    return __uint_as_float(x);
}

// is64 sniff done per-block (wave 0 ballot over first 64 int64-candidate slots)
__device__ __forceinline__ int sniff_is64(const int* __restrict__ ei32, int* s64p) {
    if (threadIdx.x < 64) {
        int nz = ei32[1 + 2 * threadIdx.x] | ei32[129 + 2 * threadIdx.x];
        unsigned long long b = __ballot(nz != 0);
        if (threadIdx.x == 0) *s64p = (b == 0ull) ? 1 : 0;
    }
    __syncthreads();
    return *s64p;
}

__device__ __forceinline__ int load_node(const int* ei32, int is64, long long idx) {
    return is64 ? ei32[2 * idx] : ei32[idx];
}

// ---- merged prep: conv(x->bf16) | wconv3 (W->Wt bf16) | deg histogram ----
__global__ __launch_bounds__(256) void prep_kernel(const float* __restrict__ x,
                                                   unsigned short* __restrict__ xb,
                                                   const float* __restrict__ W1,
                                                   const float* __restrict__ W2,
                                                   const float* __restrict__ W3,
                                                   unsigned short* __restrict__ Wt1,
                                                   unsigned short* __restrict__ Wt2,
                                                   unsigned short* __restrict__ Wt3,
                                                   const int* __restrict__ ei32,
                                                   int* __restrict__ deg) {
    __shared__ float sm[32][33];
    __shared__ int s64;
    int bid = blockIdx.x;
    if (bid < NB_CONV) {
        int i = (bid * 256 + threadIdx.x) * 8;
        if (i + 8 > NN * FIN) return;
        float4 f0 = *(const float4*)(x + i);
        float4 f1 = *(const float4*)(x + i + 4);
        uint4 pk;
        pk.x = cvtpk(f0.x, f0.y);
        pk.y = cvtpk(f0.z, f0.w);
        pk.z = cvtpk(f1.x, f1.y);
        pk.w = cvtpk(f1.z, f1.w);
        *(uint4*)(xb + i) = pk;
    } else if (bid < NB_CONV + NB_WCONV) {
        int wb = bid - NB_CONV;
        int z = wb >> 6;
        int ky = (wb >> 3) & 7;
        int nx = wb & 7;
        const float* W = (z == 0) ? W1 : (z == 1) ? W2 : W3;
        unsigned short* Wt = (z == 0) ? Wt1 : (z == 1) ? Wt2 : Wt3;
        int K = (z == 0) ? FIN : HDIM;
        int k0 = ky * 32;
        if (k0 >= K) return;
        int tx = threadIdx.x & 31, ty = threadIdx.x >> 5;
        int n0 = nx * 32;
#pragma unroll
        for (int j = 0; j < 4; j++)
            sm[ty + j * 8][tx] = W[(size_t)(k0 + ty + j * 8) * HDIM + n0 + tx];
        __syncthreads();
#pragma unroll
        for (int j = 0; j < 4; j++)
            Wt[(size_t)(n0 + ty + j * 8) * K + k0 + tx] = f2b(sm[tx][ty + j * 8]);
    } else {
        int is64 = sniff_is64(ei32, &s64);
        int e = (bid - NB_CONV - NB_WCONV) * 256 + threadIdx.x;
        if (e >= ET) return;
        int d = (e < NE) ? load_node(ei32, is64, (long long)NE + e) : (e - NE);
        atomicAdd(&deg[d], 1);
    }
}

__global__ void scan1(const int* __restrict__ deg, int* __restrict__ incl,
                      int* __restrict__ bsum) {
    __shared__ int sm[256];
    int i = blockIdx.x * 256 + threadIdx.x;
    int v = (i < NN) ? deg[i] : 0;
    sm[threadIdx.x] = v;
    __syncthreads();
    for (int o = 1; o < 256; o <<= 1) {
        int add = (threadIdx.x >= o) ? sm[threadIdx.x - o] : 0;
        __syncthreads();
        sm[threadIdx.x] += add;
        __syncthreads();
    }
    if (i < NN) incl[i] = sm[threadIdx.x];
    if (threadIdx.x == 255) bsum[blockIdx.x] = sm[255];
}

__global__ void scan2(int* __restrict__ bsum) {
    __shared__ int sm[256];
    int t = threadIdx.x;
    sm[t] = (t < NB_SCAN) ? bsum[t] : 0;
    __syncthreads();
    if (t == 0) {
        int run = 0;
        for (int b = 0; b < NB_SCAN; b++) { int v = sm[b]; sm[b] = run; run += v; }
    }
    __syncthreads();
    if (t < NB_SCAN) bsum[t] = sm[t];
}

__global__ void scan3(const int* __restrict__ incl, const int* __restrict__ bsum,
                      const int* __restrict__ deg, int* __restrict__ indptr,
                      int* __restrict__ cursor) {
    int i = blockIdx.x * 256 + threadIdx.x;
    if (i < NN) {
        int v = bsum[blockIdx.x] + incl[i];
        indptr[i + 1] = v;
        cursor[i] = v - deg[i];
    }
    if (i == 0) indptr[0] = 0;
}

// ------- GEMM body: 128x128 tile, 512 threads (8 waves, each 32 rows x 64 cols) -------
// A refetched only 2x (2 col-blocks, same XCD via swizzle). Fused alpha; LDS-bounce C.
__device__ __forceinline__ void gemm_body(const unsigned short* __restrict__ A,
                                          const unsigned short* __restrict__ Bt,
                                          unsigned short* __restrict__ Cb,
                                          const float* __restrict__ a_s,
                                          const float* __restrict__ a_d,
                                          float* __restrict__ als,
                                          float* __restrict__ ald,
                                          int M, int K, int bid) {
    __shared__ unsigned short As[128][72];
    __shared__ unsigned short Bs[128][72];
    int xcd = bid & 7, g = bid >> 3;
    int cblk = g & 1, rg = g >> 1;
    int rblk = rg * 8 + xcd;
    int r0 = rblk * 128, n0 = cblk * 128;
    if (r0 >= M) return;

    int t = threadIdx.x;            // 0..511
    int lane = t & 63, w8 = t >> 6; // 8 waves
    int wr = w8 & 3, wc = w8 >> 2;  // wave -> 32-row group, 64-col group
    int fr = lane & 15, kg = lane >> 4, kf = kg * 8;

    f32x4 acc[2][4];
#pragma unroll
    for (int m = 0; m < 2; m++)
#pragma unroll
        for (int n = 0; n < 4; n++)
            acc[m][n] = (f32x4){0.f, 0.f, 0.f, 0.f};

    int s0 = t, s1 = t + 512;       // 1024 slots: row = s>>3, k-octet = s&7
    int ar0 = r0 + (s0 >> 3); if (ar0 > M - 1) ar0 = M - 1;
    int ar1 = r0 + (s1 >> 3); if (ar1 > M - 1) ar1 = M - 1;
    const unsigned short* gA0 = A + (size_t)ar0 * K + (s0 & 7) * 8;
    const unsigned short* gA1 = A + (size_t)ar1 * K + (s1 & 7) * 8;
    const unsigned short* gB0 = Bt + (size_t)(n0 + (s0 >> 3)) * K + (s0 & 7) * 8;
    const unsigned short* gB1 = Bt + (size_t)(n0 + (s1 >> 3)) * K + (s1 & 7) * 8;

    for (int k0 = 0; k0 < K; k0 += 64) {
        *(uint4*)&As[s0 >> 3][(s0 & 7) * 8] = *(const uint4*)(gA0 + k0);
        *(uint4*)&As[s1 >> 3][(s1 & 7) * 8] = *(const uint4*)(gA1 + k0);
        *(uint4*)&Bs[s0 >> 3][(s0 & 7) * 8] = *(const uint4*)(gB0 + k0);
        *(uint4*)&Bs[s1 >> 3][(s1 & 7) * 8] = *(const uint4*)(gB1 + k0);
        __syncthreads();
#pragma unroll
        for (int kk = 0; kk < 64; kk += 32) {
            bf16x8 a[2], b[4];
#pragma unroll
            for (int m = 0; m < 2; m++)
                a[m] = *(const bf16x8*)&As[wr * 32 + m * 16 + fr][kk + kf];
#pragma unroll
            for (int n = 0; n < 4; n++)
                b[n] = *(const bf16x8*)&Bs[wc * 64 + n * 16 + fr][kk + kf];
#pragma unroll
            for (int m = 0; m < 2; m++)
#pragma unroll
                for (int n = 0; n < 4; n++)
                    acc[m][n] = __builtin_amdgcn_mfma_f32_16x16x32_bf16(a[m], b[n], acc[m][n], 0, 0, 0);
        }
        __syncthreads();
    }

    // ---- fused alpha (head = cblk*2 + wc; each (row,head) owned by one wave) ----
    int head = cblk * 2 + wc;
    float asv[4], adv[4];
#pragma unroll
    for (int n = 0; n < 4; n++) {
        asv[n] = a_s[n0 + wc * 64 + n * 16 + fr];
        adv[n] = a_d[n0 + wc * 64 + n * 16 + fr];
    }
#pragma unroll
    for (int m = 0; m < 2; m++)
#pragma unroll
        for (int q = 0; q < 4; q++) {
            int gr = r0 + wr * 32 + m * 16 + kg * 4 + q;
            float vs = 0.f, vd = 0.f;
#pragma unroll
            for (int n = 0; n < 4; n++) {
                float v = acc[m][n][q];
                vs += v * asv[n];
                vd += v * adv[n];
            }
#pragma unroll
            for (int o = 8; o > 0; o >>= 1) {
                vs += __shfl_xor(vs, o);
                vd += __shfl_xor(vd, o);
            }
            if (fr == 0 && gr < M) {
                als[gr * NHEAD + head] = vs;
                ald[gr * NHEAD + head] = vd;
            }
        }

    // ---- C store: LDS bounce Cs[128][136] over As+Bs -> coalesced uint4 stores ----
    unsigned short (*Cs)[136] = (unsigned short(*)[136])&As[0][0];   // 34 KB <= 36 KB
#pragma unroll
    for (int m = 0; m < 2; m++)
#pragma unroll
        for (int q = 0; q < 4; q++)
#pragma unroll
            for (int n = 0; n < 4; n++)
                Cs[wr * 32 + m * 16 + kg * 4 + q][wc * 64 + n * 16 + fr] = f2b(acc[m][n][q]);
    __syncthreads();
    int row = t >> 2, u = t & 3;
    int gr = r0 + row;
    if (gr < M) {
#pragma unroll
        for (int j = 0; j < 4; j++) {
            int col0 = u * 32 + j * 8;
            *(uint4*)(Cb + (size_t)gr * HDIM + n0 + col0) = *(const uint4*)&Cs[row][col0];
        }
    }
}

__global__ __launch_bounds__(512) void gemm_mfma(const unsigned short* __restrict__ A,
                                                 const unsigned short* __restrict__ Bt,
                                                 unsigned short* __restrict__ Cb,
                                                 const float* __restrict__ a_s,
                                                 const float* __restrict__ a_d,
                                                 float* __restrict__ als,
                                                 float* __restrict__ ald,
                                                 int M, int K) {
    gemm_body(A, Bt, Cb, a_s, a_d, als, ald, M, K, blockIdx.x);
}

// ---- merged: gemm layer 1 (blocks 0..GG-1) | CSR fill (blocks GG..) ----
__global__ __launch_bounds__(512) void gemm1_fill_kernel(const unsigned short* __restrict__ A,
                                                         const unsigned short* __restrict__ Bt,
                                                         unsigned short* __restrict__ Cb,
                                                         const float* __restrict__ a_s,
                                                         const float* __restrict__ a_d,
                                                         float* __restrict__ als,
                                                         float* __restrict__ ald,
                                                         const int* __restrict__ ei32,
                                                         int* __restrict__ cursor,
                                                         int* __restrict__ esrc) {
    __shared__ int s64;
    int bid = blockIdx.x;
    if (bid < GG) {
        gemm_body(A, Bt, Cb, a_s, a_d, als, ald, NN, FIN, bid);
    } else {
        int is64 = sniff_is64(ei32, &s64);
        int e = (bid - GG) * 512 + threadIdx.x;
        if (e >= ET) return;
        int s, d;
        if (e < NE) {
            s = load_node(ei32, is64, (long long)e);
            d = load_node(ei32, is64, (long long)NE + e);
        } else {
            s = d = e - NE;
        }
        int pos = atomicAdd(&cursor[d], 1);
        esrc[pos] = s;
    }
}

// ---- agg: one WAVE per node; pair-chunk pipeline issues 32 gathers back-to-back ----
__global__ __launch_bounds__(256) void agg_kernel(const unsigned short* __restrict__ projb,
                                                  const float* __restrict__ als,
                                                  const float* __restrict__ ald,
                                                  const int* __restrict__ indptr,
                                                  const int* __restrict__ esrc,
                                                  const float* __restrict__ bias,
                                                  unsigned short* __restrict__ featb) {
    int wid = threadIdx.x >> 6;
    int v = blockIdx.x * 4 + wid;
    if (v >= NN) return;
    int lane = threadIdx.x & 63;
    int h = lane >> 4;
    int sub = lane & 15;
    int beg = indptr[v], end = indptr[v + 1];
    float adv = ald[v * NHEAD + h];

    // ---- phase 1: online (max,sumexp); cache (s,e) for first 2 chunks ----
    float e0 = 0.f, e1 = 0.f;
    int s0r = 0, s1r = 0;
    float m = -INFINITY, ss = 0.f;
    int idx = 0;
    for (int i = beg + sub; i < end; i += 16, idx++) {
        int s = esrc[i];
        float e = als[s * NHEAD + h] + adv;
        e = e > 0.f ? e : NEG * e;
        if (idx == 0) { e0 = e; s0r = s; }
        else if (idx == 1) { e1 = e; s1r = s; }
        if (e > m) {
            ss = ss * __expf(m - e) + 1.f;
            m = e;
        } else {
            ss += __expf(e - m);
        }
    }
#pragma unroll
    for (int o = 8; o > 0; o >>= 1) {
        float m2 = __shfl_xor(m, o);
        float s2 = __shfl_xor(ss, o);
        float mn = fmaxf(m, m2);
        float a = (m == mn) ? ss : ss * __expf(m - mn);
        float b = (m2 == mn) ? s2 : s2 * __expf(m2 - mn);
        m = mn;
        ss = a + b;
    }
    float inv = 1.f / (ss + 1e-16f);

    float4 acc = make_float4(0.f, 0.f, 0.f, 0.f);
    int c = beg;
    int chunk = 0;
    // ---- paired chunks: 32 gathers in flight before any FMA ----
    for (; c + 16 < end; c += 32, chunk += 2) {
        int remB = end - (c + 16); if (remB > 16) remB = 16;
        int sA, sB;
        float eA, eB;
        if (chunk == 0) {
            sA = s0r; eA = e0;
            sB = s1r; eB = e1;
        } else {
            sA = esrc[c + sub];
            eA = als[sA * NHEAD + h] + adv;
            eA = eA > 0.f ? eA : NEG * eA;
            int iB = c + 16 + (sub < remB ? sub : remB - 1);
            sB = esrc[iB];
            eB = als[sB * NHEAD + h] + adv;
            eB = eB > 0.f ? eB : NEG * eB;
        }
        float wA = __expf(eA - m) * inv;
        float wB = (sub < remB) ? __expf(eB - m) * inv : 0.f;

        ushort4 pA[16], pB[16];
#pragma unroll
        for (int j = 0; j < 16; j++) {
            int s = __shfl(sA, j);
            pA[j] = *(const ushort4*)(projb + (size_t)s * HDIM + (lane << 2));
        }
#pragma unroll
        for (int j = 0; j < 16; j++) {
            int s = __shfl(sB, j);
            pB[j] = *(const ushort4*)(projb + (size_t)s * HDIM + (lane << 2));
        }
#pragma unroll
        for (int j = 0; j < 16; j++) {
            float w = __shfl(wA, (h << 4) | j);
            acc.x += b2f(pA[j].x) * w;
            acc.y += b2f(pA[j].y) * w;
            acc.z += b2f(pA[j].z) * w;
            acc.w += b2f(pA[j].w) * w;
        }
#pragma unroll
        for (int j = 0; j < 16; j++) {
            float w = __shfl(wB, (h << 4) | j);
            acc.x += b2f(pB[j].x) * w;
            acc.y += b2f(pB[j].y) * w;
            acc.z += b2f(pB[j].z) * w;
            acc.w += b2f(pB[j].w) * w;
        }
    }
    // ---- single remaining chunk (1..16 edges) ----
    if (c < end) {
        int rem = end - c;
        int sA;
        float eA;
        if (chunk == 0) { sA = s0r; eA = e0; }
        else if (chunk == 1) { sA = s1r; eA = e1; }
        else {
            int i = c + (sub < rem ? sub : rem - 1);
            sA = esrc[i];
            eA = als[sA * NHEAD + h] + adv;
            eA = eA > 0.f ? eA : NEG * eA;
        }
        float wA = (sub < rem) ? __expf(eA - m) * inv : 0.f;
        ushort4 p[16];
#pragma unroll
        for (int j = 0; j < 16; j++) {
            int s = __shfl(sA, j);
            p[j] = *(const ushort4*)(projb + (size_t)s * HDIM + (lane << 2));
        }
#pragma unroll
        for (int j = 0; j < 16; j++) {
            float w = __shfl(wA, (h << 4) | j);
            acc.x += b2f(p[j].x) * w;
            acc.y += b2f(p[j].y) * w;
            acc.z += b2f(p[j].z) * w;
            acc.w += b2f(p[j].w) * w;
        }
    }

    const float4 b4 = *(const float4*)(bias + (lane << 2));
    float4 r;
    r.x = acc.x + b4.x;
    r.y = acc.y + b4.y;
    r.z = acc.z + b4.z;
    r.w = acc.w + b4.w;
    r.x = r.x > 0.f ? r.x : __expf(r.x) - 1.f;
    r.y = r.y > 0.f ? r.y : __expf(r.y) - 1.f;
    r.z = r.z > 0.f ? r.z : __expf(r.z) - 1.f;
    r.w = r.w > 0.f ? r.w : __expf(r.w) - 1.f;
    uint2 o2;
    o2.x = cvtpk(r.x, r.y);
    o2.y = cvtpk(r.z, r.w);
    *(uint2*)(featb + (size_t)v * HDIM + (lane << 2)) = o2;
}

// ---- final linear [256->40] + log_softmax (bf16 features), class dim padded to 64 ----
__global__ __launch_bounds__(256) void final_kernel(const unsigned short* __restrict__ featb,
                                                    const float* __restrict__ Wl,
                                                    const float* __restrict__ bl,
                                                    float* __restrict__ out) {
    const int BK = 16;
    __shared__ float As[BK][65];
    __shared__ float Bs[BK][65];
    int tx = threadIdx.x & 15, ty = threadIdx.x >> 4;
    int row0 = blockIdx.x * 64;
    float acc[4][4] = {};
    for (int k0 = 0; k0 < HDIM; k0 += BK) {
#pragma unroll
        for (int i = 0; i < 4; i++) {
            int l = threadIdx.x + 256 * i;
            int r = l >> 4, c = l & 15;
            int gr = row0 + r;
            float v = 0.f;
            if (gr < NN) v = b2f(featb[(size_t)gr * HDIM + k0 + c]);
            As[c][r] = v;
        }
#pragma unroll
        for (int i = 0; i < 4; i++) {
            int l = threadIdx.x + 256 * i;
            int r = l >> 6, c = l & 63;
            Bs[r][c] = (c < NCLS) ? Wl[(size_t)(k0 + r) * NCLS + c] : 0.f;
        }
        __syncthreads();
#pragma unroll
        for (int k = 0; k < BK; k++) {
            float a[4], b[4];
#pragma unroll
            for (int i = 0; i < 4; i++) a[i] = As[k][ty + 16 * i];
#pragma unroll
            for (int j = 0; j < 4; j++) b[j] = Bs[k][tx + 16 * j];
#pragma unroll
            for (int i = 0; i < 4; i++)
#pragma unroll
                for (int j = 0; j < 4; j++) acc[i][j] += a[i] * b[j];
        }
        __syncthreads();
    }
    float b0 = bl[tx], b1 = bl[tx + 16], b2 = (tx < 8) ? bl[tx + 32] : 0.f;
#pragma unroll
    for (int i = 0; i < 4; i++) {
        int gr = row0 + ty + 16 * i;
        if (gr >= NN) continue;
        float l0 = acc[i][0] + b0;
        float l1 = acc[i][1] + b1;
        float l2 = (tx < 8) ? acc[i][2] + b2 : -INFINITY;
        float m = fmaxf(fmaxf(l0, l1), l2);
#pragma unroll
        for (int o = 8; o > 0; o >>= 1) m = fmaxf(m, __shfl_xor(m, o));
        float s = __expf(l0 - m) + __expf(l1 - m) + ((tx < 8) ? __expf(l2 - m) : 0.f);
#pragma unroll
        for (int o = 8; o > 0; o >>= 1) s += __shfl_xor(s, o);
        float lse = m + __logf(s);
        out[(size_t)gr * NCLS + tx] = l0 - lse;
        out[(size_t)gr * NCLS + tx + 16] = l1 - lse;
        if (tx < 8) out[(size_t)gr * NCLS + tx + 32] = l2 - lse;
    }
}

extern "C" void kernel_launch(void* const* d_in, const int* in_sizes, int n_in,
                              void* d_out, int out_size, void* d_ws, size_t ws_size,
                              hipStream_t stream) {
    const float* x  = (const float*)d_in[0];
    const int* ei32 = (const int*)d_in[1];
    const float* W1 = (const float*)d_in[2];
    const float* as1 = (const float*)d_in[3];
    const float* ad1 = (const float*)d_in[4];
    const float* b1 = (const float*)d_in[5];
    const float* W2 = (const float*)d_in[6];
    const float* as2 = (const float*)d_in[7];
    const float* ad2 = (const float*)d_in[8];
    const float* b2 = (const float*)d_in[9];
    const float* W3 = (const float*)d_in[10];
    const float* as3 = (const float*)d_in[11];
    const float* ad3 = (const float*)d_in[12];
    const float* b3 = (const float*)d_in[13];
    const float* Wl = (const float*)d_in[14];
    const float* bl = (const float*)d_in[15];
    float* out = (float*)d_out;

    // workspace layout
    char* w = (char*)d_ws;
    unsigned short* projb = (unsigned short*)w;  w += (size_t)NN * HDIM * 2;
    unsigned short* featb = (unsigned short*)w;  w += (size_t)NN * HDIM * 2;
    unsigned short* xb    = (unsigned short*)w;  w += (size_t)NN * FIN * 2;
    unsigned short* Wt1b  = (unsigned short*)w;  w += (size_t)HDIM * FIN * 2;
    unsigned short* Wt2b  = (unsigned short*)w;  w += (size_t)HDIM * HDIM * 2;
    unsigned short* Wt3b  = (unsigned short*)w;  w += (size_t)HDIM * HDIM * 2;
    float* als  = (float*)w;  w += (size_t)NN * NHEAD * 4;
    float* ald  = (float*)w;  w += (size_t)NN * NHEAD * 4;
    int* deg    = (int*)w;    w += (size_t)NN * 4;
    int* incl   = (int*)w;    w += (size_t)NN * 4;
    int* bsum   = (int*)w;    w += 256 * 4;
    int* indptr = (int*)w;    w += (size_t)(NN + 1) * 4;
    int* cursor = (int*)w;    w += (size_t)NN * 4;
    int* esrc   = (int*)w;    w += (size_t)ET * 4;

    // ---- merged prep: conv + wconv3 + deg histogram ----
    hipMemsetAsync(deg, 0, (size_t)NN * 4, stream);
    prep_kernel<<<NB_CONV + NB_WCONV + NB_EDGE, 256, 0, stream>>>(
        x, xb, W1, W2, W3, Wt1b, Wt2b, Wt3b, ei32, deg);

    // ---- CSR scan ----
    scan1<<<NB_SCAN, 256, 0, stream>>>(deg, incl, bsum);
    scan2<<<1, 256, 0, stream>>>(bsum);
    scan3<<<NB_SCAN, 256, 0, stream>>>(incl, bsum, deg, indptr, cursor);

    int agrid = (NN + 3) / 4;

    // ---- layer 1 GEMM merged with CSR fill (independent; fill hides under MFMA) ----
    gemm1_fill_kernel<<<GG + NB_FILL, 512, 0, stream>>>(
        xb, Wt1b, projb, as1, ad1, als, ald, ei32, cursor, esrc);
    agg_kernel<<<agrid, 256, 0, stream>>>(projb, als, ald, indptr, esrc, b1, featb);
    // ---- layer 2 ----
    gemm_mfma<<<GG, 512, 0, stream>>>(featb, Wt2b, projb, as2, ad2, als, ald, NN, HDIM);
    agg_kernel<<<agrid, 256, 0, stream>>>(projb, als, ald, indptr, esrc, b2, featb);
    // ---- layer 3 ----
    gemm_mfma<<<GG, 512, 0, stream>>>(featb, Wt3b, projb, as3, ad3, als, ald, NN, HDIM);
    agg_kernel<<<agrid, 256, 0, stream>>>(projb, als, ald, indptr, esrc, b3, featb);
    // ---- final linear + log_softmax (fused) ----
    final_kernel<<<(NN + 63) / 64, 256, 0, stream>>>(featb, Wl, bl, out);
}

// Round 18
// 404.028 us; speedup vs baseline: 1.0647x; 1.0647x over previous
//
#include <hip/hip_runtime.h>
#include <math.h>

#define NN 50000
#define NE 800000
#define ET (NE + NN)          // edges + self loops = 850000
#define FIN 128
#define HDIM 256
#define NHEAD 4
#define NCLS 40
#define NEG 0.2f
#define NB_SCAN ((NN + 255) / 256)   // 196
#define NB_CONV 3125                 // NN*FIN/8/256
#define NB_WCONV 192                 // 8*8*3
#define NB_EDGE ((ET + 255) / 256)   // 3322

typedef short bf16x8 __attribute__((ext_vector_type(8)));
typedef float f32x4 __attribute__((ext_vector_type(4)));

__device__ __forceinline__ unsigned short f2b(float f) {
    unsigned int u = __float_as_uint(f);
    unsigned int r = (u + 0x7fffu + ((u >> 16) & 1u)) >> 16;
    return (unsigned short)r;
}
__device__ __forceinline__ unsigned int cvtpk(float lo, float hi) {
    unsigned int r;
    asm volatile("v_cvt_pk_bf16_f32 %0, %1, %2" : "=v"(r) : "v"(lo), "v"(hi));
    return r;
}
__device__ __forceinline__ float b2f(unsigned short u) {
    unsigned int x = ((unsigned int)u) << 16;
    return __uint_as_float(x);
}

// is64 sniff done per-block (wave 0 ballot over first 64 int64-candidate slots)
__device__ __forceinline__ int sniff_is64(const int* __restrict__ ei32, int* s64p) {
    if (threadIdx.x < 64) {
        int nz = ei32[1 + 2 * threadIdx.x] | ei32[129 + 2 * threadIdx.x];
        unsigned long long b = __ballot(nz != 0);
        if (threadIdx.x == 0) *s64p = (b == 0ull) ? 1 : 0;
    }
    __syncthreads();
    return *s64p;
}

__device__ __forceinline__ int load_node(const int* ei32, int is64, long long idx) {
    return is64 ? ei32[2 * idx] : ei32[idx];
}

// ---- merged prep: conv(x->bf16) | wconv3 (W->Wt bf16) | deg histogram ----
__global__ __launch_bounds__(256) void prep_kernel(const float* __restrict__ x,
                                                   unsigned short* __restrict__ xb,
                                                   const float* __restrict__ W1,
                                                   const float* __restrict__ W2,
                                                   const float* __restrict__ W3,
                                                   unsigned short* __restrict__ Wt1,
                                                   unsigned short* __restrict__ Wt2,
                                                   unsigned short* __restrict__ Wt3,
                                                   const int* __restrict__ ei32,
                                                   int* __restrict__ deg) {
    __shared__ float sm[32][33];
    __shared__ int s64;
    int bid = blockIdx.x;
    if (bid < NB_CONV) {
        // ---- x f32 -> bf16 ----
        int i = (bid * 256 + threadIdx.x) * 8;
        if (i + 8 > NN * FIN) return;
        float4 f0 = *(const float4*)(x + i);
        float4 f1 = *(const float4*)(x + i + 4);
        uint4 pk;
        pk.x = cvtpk(f0.x, f0.y);
        pk.y = cvtpk(f0.z, f0.w);
        pk.z = cvtpk(f1.x, f1.y);
        pk.w = cvtpk(f1.z, f1.w);
        *(uint4*)(xb + i) = pk;
    } else if (bid < NB_CONV + NB_WCONV) {
        // ---- W[K][256] -> Wt[256][K] bf16 ----
        int wb = bid - NB_CONV;
        int z = wb >> 6;              // layer
        int ky = (wb >> 3) & 7;       // k0/32
        int nx = wb & 7;              // n0/32
        const float* W = (z == 0) ? W1 : (z == 1) ? W2 : W3;
        unsigned short* Wt = (z == 0) ? Wt1 : (z == 1) ? Wt2 : Wt3;
        int K = (z == 0) ? FIN : HDIM;
        int k0 = ky * 32;
        if (k0 >= K) return;
        int tx = threadIdx.x & 31, ty = threadIdx.x >> 5;   // 32 x 8
        int n0 = nx * 32;
#pragma unroll
        for (int j = 0; j < 4; j++)
            sm[ty + j * 8][tx] = W[(size_t)(k0 + ty + j * 8) * HDIM + n0 + tx];
        __syncthreads();
#pragma unroll
        for (int j = 0; j < 4; j++)
            Wt[(size_t)(n0 + ty + j * 8) * K + k0 + tx] = f2b(sm[tx][ty + j * 8]);
    } else {
        // ---- degree histogram ----
        int is64 = sniff_is64(ei32, &s64);
        int e = (bid - NB_CONV - NB_WCONV) * 256 + threadIdx.x;
        if (e >= ET) return;
        int d = (e < NE) ? load_node(ei32, is64, (long long)NE + e) : (e - NE);
        atomicAdd(&deg[d], 1);
    }
}

__global__ void scan1(const int* __restrict__ deg, int* __restrict__ incl,
                      int* __restrict__ bsum) {
    __shared__ int sm[256];
    int i = blockIdx.x * 256 + threadIdx.x;
    int v = (i < NN) ? deg[i] : 0;
    sm[threadIdx.x] = v;
    __syncthreads();
    for (int o = 1; o < 256; o <<= 1) {
        int add = (threadIdx.x >= o) ? sm[threadIdx.x - o] : 0;
        __syncthreads();
        sm[threadIdx.x] += add;
        __syncthreads();
    }
    if (i < NN) incl[i] = sm[threadIdx.x];
    if (threadIdx.x == 255) bsum[blockIdx.x] = sm[255];
}

__global__ void scan2(int* __restrict__ bsum) {
    __shared__ int sm[256];
    int t = threadIdx.x;
    sm[t] = (t < NB_SCAN) ? bsum[t] : 0;
    __syncthreads();
    if (t == 0) {
        int run = 0;
        for (int b = 0; b < NB_SCAN; b++) { int v = sm[b]; sm[b] = run; run += v; }
    }
    __syncthreads();
    if (t < NB_SCAN) bsum[t] = sm[t];
}

__global__ void scan3(const int* __restrict__ incl, const int* __restrict__ bsum,
                      const int* __restrict__ deg, int* __restrict__ indptr,
                      int* __restrict__ cursor) {
    int i = blockIdx.x * 256 + threadIdx.x;
    if (i < NN) {
        int v = bsum[blockIdx.x] + incl[i];
        indptr[i + 1] = v;
        cursor[i] = v - deg[i];
    }
    if (i == 0) indptr[0] = 0;
}

__global__ void fill_kernel(const int* __restrict__ ei32,
                            int* __restrict__ cursor, int* __restrict__ esrc) {
    __shared__ int s64;
    int is64 = sniff_is64(ei32, &s64);
    int e = blockIdx.x * blockDim.x + threadIdx.x;
    if (e >= ET) return;
    int s, d;
    if (e < NE) {
        s = load_node(ei32, is64, (long long)e);
        d = load_node(ei32, is64, (long long)NE + e);
    } else {
        s = d = e - NE;
    }
    int pos = atomicAdd(&cursor[d], 1);
    esrc[pos] = s;
}

// ------- MFMA GEMM (bf16 A) + fused alpha (R11 structure: VGPR staging, padded LDS) -------
// 1D grid with XCD-aware swizzle: all 4 col-blocks of a row-panel share bid%8 -> same XCD.
__global__ __launch_bounds__(256) void gemm_mfma(const unsigned short* __restrict__ A,
                                                 const unsigned short* __restrict__ Bt,
                                                 unsigned short* __restrict__ Cb,
                                                 const float* __restrict__ a_s,
                                                 const float* __restrict__ a_d,
                                                 float* __restrict__ als,
                                                 float* __restrict__ ald,
                                                 int M, int K) {
    __shared__ unsigned short As[128][72];   // stride 144 B -> 2-way bank alias (free)
    __shared__ unsigned short Bs[64][72];
    int bid = blockIdx.x;
    int xcd = bid & 7, g = bid >> 3;
    int cblk = g & 3, rg = g >> 2;
    int rblk = rg * 8 + xcd;
    int r0 = rblk * 128, n0 = cblk * 64;
    if (r0 >= M) return;

    int t = threadIdx.x;
    int lane = t & 63, wid = t >> 6;

    f32x4 acc[2][4];
#pragma unroll
    for (int m = 0; m < 2; m++)
#pragma unroll
        for (int n = 0; n < 4; n++)
            acc[m][n] = (f32x4){0.f, 0.f, 0.f, 0.f};

    int ar = t >> 1, ah = (t & 1) * 32;
    int arow = r0 + ar; if (arow > M - 1) arow = M - 1;
    const unsigned short* ga = A + (size_t)arow * K + ah;
    int bn = t >> 2, bq = (t & 3) * 16;
    const unsigned short* gb = Bt + (size_t)(n0 + bn) * K + bq;

    int fr = lane & 15;          // frag row/col within 16
    int kf = (lane >> 4) * 8;    // k-octet

    for (int k0 = 0; k0 < K; k0 += 64) {
#pragma unroll
        for (int j = 0; j < 4; j++)
            *(uint4*)&As[ar][ah + j * 8] = *(const uint4*)(ga + k0 + j * 8);
#pragma unroll
        for (int j = 0; j < 2; j++)
            *(uint4*)&Bs[bn][bq + j * 8] = *(const uint4*)(gb + k0 + j * 8);
        __syncthreads();
#pragma unroll
        for (int kk = 0; kk < 64; kk += 32) {
            bf16x8 a[2], b[4];
#pragma unroll
            for (int m = 0; m < 2; m++)
                a[m] = *(const bf16x8*)&As[wid * 32 + m * 16 + fr][kk + kf];
#pragma unroll
            for (int n = 0; n < 4; n++)
                b[n] = *(const bf16x8*)&Bs[n * 16 + fr][kk + kf];
#pragma unroll
            for (int m = 0; m < 2; m++)
#pragma unroll
                for (int n = 0; n < 4; n++)
                    acc[m][n] = __builtin_amdgcn_mfma_f32_16x16x32_bf16(a[m], b[n], acc[m][n], 0, 0, 0);
        }
        __syncthreads();
    }

    // ---- fused alpha reduction (register-level, before LDS reuse) ----
    int rbase = r0 + wid * 32 + (lane >> 4) * 4;
    int cbase = n0 + fr;
    int head = n0 >> 6;
    float asv[4], adv[4];
#pragma unroll
    for (int n = 0; n < 4; n++) {
        asv[n] = a_s[cbase + n * 16];
        adv[n] = a_d[cbase + n * 16];
    }
#pragma unroll
    for (int m = 0; m < 2; m++)
#pragma unroll
        for (int q = 0; q < 4; q++) {
            int gr = rbase + m * 16 + q;
            float vs = 0.f, vd = 0.f;
#pragma unroll
            for (int n = 0; n < 4; n++) {
                float v = acc[m][n][q];
                vs += v * asv[n];
                vd += v * adv[n];
            }
#pragma unroll
            for (int o = 8; o > 0; o >>= 1) {
                vs += __shfl_xor(vs, o);
                vd += __shfl_xor(vd, o);
            }
            if (fr == 0 && gr < M) {
                als[gr * NHEAD + head] = vs;
                ald[gr * NHEAD + head] = vd;
            }
        }

    // ---- C store: LDS bounce (reuse As; [128][68] pad -> conflict-free) ----
    unsigned short (*Cs)[68] = (unsigned short(*)[68])&As[0][0];
    int lr0 = wid * 32 + (lane >> 4) * 4;
#pragma unroll
    for (int m = 0; m < 2; m++)
#pragma unroll
        for (int q = 0; q < 4; q++)
#pragma unroll
            for (int n = 0; n < 4; n++)
                Cs[lr0 + m * 16 + q][fr + n * 16] = f2b(acc[m][n][q]);
    __syncthreads();
    int tr = t >> 4;
    int tc = (t & 15) * 4;
#pragma unroll
    for (int rr = 0; rr < 8; rr++) {
        int lr = tr + rr * 16;
        int gr = r0 + lr;
        if (gr < M) *(ushort4*)(Cb + (size_t)gr * HDIM + n0 + tc) = *(const ushort4*)&Cs[lr][tc];
    }
}

// ---- agg: one WAVE per node; pair-chunk pipeline issues 32 gathers back-to-back ----
__global__ __launch_bounds__(256) void agg_kernel(const unsigned short* __restrict__ projb,
                                                  const float* __restrict__ als,
                                                  const float* __restrict__ ald,
                                                  const int* __restrict__ indptr,
                                                  const int* __restrict__ esrc,
                                                  const float* __restrict__ bias,
                                                  unsigned short* __restrict__ featb) {
    int wid = threadIdx.x >> 6;
    int v = blockIdx.x * 4 + wid;
    if (v >= NN) return;
    int lane = threadIdx.x & 63;
    int h = lane >> 4;
    int sub = lane & 15;
    int beg = indptr[v], end = indptr[v + 1];
    float adv = ald[v * NHEAD + h];

    // ---- phase 1: online (max,sumexp); cache (s,e) for first 2 chunks ----
    float e0 = 0.f, e1 = 0.f;
    int s0r = 0, s1r = 0;
    float m = -INFINITY, ss = 0.f;
    int idx = 0;
    for (int i = beg + sub; i < end; i += 16, idx++) {
        int s = esrc[i];
        float e = als[s * NHEAD + h] + adv;
        e = e > 0.f ? e : NEG * e;
        if (idx == 0) { e0 = e; s0r = s; }
        else if (idx == 1) { e1 = e; s1r = s; }
        if (e > m) {
            ss = ss * __expf(m - e) + 1.f;
            m = e;
        } else {
            ss += __expf(e - m);
        }
    }
#pragma unroll
    for (int o = 8; o > 0; o >>= 1) {
        float m2 = __shfl_xor(m, o);
        float s2 = __shfl_xor(ss, o);
        float mn = fmaxf(m, m2);
        float a = (m == mn) ? ss : ss * __expf(m - mn);
        float b = (m2 == mn) ? s2 : s2 * __expf(m2 - mn);
        m = mn;
        ss = a + b;
    }
    float inv = 1.f / (ss + 1e-16f);

    float4 acc = make_float4(0.f, 0.f, 0.f, 0.f);
    int c = beg;
    int chunk = 0;
    // ---- paired chunks: 32 gathers in flight before any FMA ----
    for (; c + 16 < end; c += 32, chunk += 2) {
        int remB = end - (c + 16); if (remB > 16) remB = 16;
        int sA, sB;
        float eA, eB;
        if (chunk == 0) {
            sA = s0r; eA = e0;
            sB = s1r; eB = e1;
        } else {
            sA = esrc[c + sub];
            eA = als[sA * NHEAD + h] + adv;
            eA = eA > 0.f ? eA : NEG * eA;
            int iB = c + 16 + (sub < remB ? sub : remB - 1);
            sB = esrc[iB];
            eB = als[sB * NHEAD + h] + adv;
            eB = eB > 0.f ? eB : NEG * eB;
        }
        float wA = __expf(eA - m) * inv;
        float wB = (sub < remB) ? __expf(eB - m) * inv : 0.f;

        ushort4 pA[16], pB[16];
#pragma unroll
        for (int j = 0; j < 16; j++) {
            int s = __shfl(sA, j);
            pA[j] = *(const ushort4*)(projb + (size_t)s * HDIM + (lane << 2));
        }
#pragma unroll
        for (int j = 0; j < 16; j++) {
            int s = __shfl(sB, j);
            pB[j] = *(const ushort4*)(projb + (size_t)s * HDIM + (lane << 2));
        }
#pragma unroll
        for (int j = 0; j < 16; j++) {
            float w = __shfl(wA, (h << 4) | j);
            acc.x += b2f(pA[j].x) * w;
            acc.y += b2f(pA[j].y) * w;
            acc.z += b2f(pA[j].z) * w;
            acc.w += b2f(pA[j].w) * w;
        }
#pragma unroll
        for (int j = 0; j < 16; j++) {
            float w = __shfl(wB, (h << 4) | j);
            acc.x += b2f(pB[j].x) * w;
            acc.y += b2f(pB[j].y) * w;
            acc.z += b2f(pB[j].z) * w;
            acc.w += b2f(pB[j].w) * w;
        }
    }
    // ---- single remaining chunk (1..16 edges) ----
    if (c < end) {
        int rem = end - c;
        int sA;
        float eA;
        if (chunk == 0) { sA = s0r; eA = e0; }
        else if (chunk == 1) { sA = s1r; eA = e1; }
        else {
            int i = c + (sub < rem ? sub : rem - 1);
            sA = esrc[i];
            eA = als[sA * NHEAD + h] + adv;
            eA = eA > 0.f ? eA : NEG * eA;
        }
        float wA = (sub < rem) ? __expf(eA - m) * inv : 0.f;
        ushort4 p[16];
#pragma unroll
        for (int j = 0; j < 16; j++) {
            int s = __shfl(sA, j);
            p[j] = *(const ushort4*)(projb + (size_t)s * HDIM + (lane << 2));
        }
#pragma unroll
        for (int j = 0; j < 16; j++) {
            float w = __shfl(wA, (h << 4) | j);
            acc.x += b2f(p[j].x) * w;
            acc.y += b2f(p[j].y) * w;
            acc.z += b2f(p[j].z) * w;
            acc.w += b2f(p[j].w) * w;
        }
    }

    const float4 b4 = *(const float4*)(bias + (lane << 2));
    float4 r;
    r.x = acc.x + b4.x;
    r.y = acc.y + b4.y;
    r.z = acc.z + b4.z;
    r.w = acc.w + b4.w;
    r.x = r.x > 0.f ? r.x : __expf(r.x) - 1.f;
    r.y = r.y > 0.f ? r.y : __expf(r.y) - 1.f;
    r.z = r.z > 0.f ? r.z : __expf(r.z) - 1.f;
    r.w = r.w > 0.f ? r.w : __expf(r.w) - 1.f;
    uint2 o2;
    o2.x = cvtpk(r.x, r.y);
    o2.y = cvtpk(r.z, r.w);
    *(uint2*)(featb + (size_t)v * HDIM + (lane << 2)) = o2;
}

// ---- final linear [256->40] + log_softmax (bf16 features), class dim padded to 64 ----
__global__ __launch_bounds__(256) void final_kernel(const unsigned short* __restrict__ featb,
                                                    const float* __restrict__ Wl,
                                                    const float* __restrict__ bl,
                                                    float* __restrict__ out) {
    const int BK = 16;
    __shared__ float As[BK][65];
    __shared__ float Bs[BK][65];
    int tx = threadIdx.x & 15, ty = threadIdx.x >> 4;
    int row0 = blockIdx.x * 64;
    float acc[4][4] = {};
    for (int k0 = 0; k0 < HDIM; k0 += BK) {
#pragma unroll
        for (int i = 0; i < 4; i++) {
            int l = threadIdx.x + 256 * i;
            int r = l >> 4, c = l & 15;
            int gr = row0 + r;
            float v = 0.f;
            if (gr < NN) v = b2f(featb[(size_t)gr * HDIM + k0 + c]);
            As[c][r] = v;
        }
#pragma unroll
        for (int i = 0; i < 4; i++) {
            int l = threadIdx.x + 256 * i;
            int r = l >> 6, c = l & 63;
            Bs[r][c] = (c < NCLS) ? Wl[(size_t)(k0 + r) * NCLS + c] : 0.f;
        }
        __syncthreads();
#pragma unroll
        for (int k = 0; k < BK; k++) {
            float a[4], b[4];
#pragma unroll
            for (int i = 0; i < 4; i++) a[i] = As[k][ty + 16 * i];
#pragma unroll
            for (int j = 0; j < 4; j++) b[j] = Bs[k][tx + 16 * j];
#pragma unroll
            for (int i = 0; i < 4; i++)
#pragma unroll
                for (int j = 0; j < 4; j++) acc[i][j] += a[i] * b[j];
        }
        __syncthreads();
    }
    float b0 = bl[tx], b1 = bl[tx + 16], b2 = (tx < 8) ? bl[tx + 32] : 0.f;
#pragma unroll
    for (int i = 0; i < 4; i++) {
        int gr = row0 + ty + 16 * i;
        if (gr >= NN) continue;
        float l0 = acc[i][0] + b0;
        float l1 = acc[i][1] + b1;
        float l2 = (tx < 8) ? acc[i][2] + b2 : -INFINITY;
        float m = fmaxf(fmaxf(l0, l1), l2);
#pragma unroll
        for (int o = 8; o > 0; o >>= 1) m = fmaxf(m, __shfl_xor(m, o));
        float s = __expf(l0 - m) + __expf(l1 - m) + ((tx < 8) ? __expf(l2 - m) : 0.f);
#pragma unroll
        for (int o = 8; o > 0; o >>= 1) s += __shfl_xor(s, o);
        float lse = m + __logf(s);
        out[(size_t)gr * NCLS + tx] = l0 - lse;
        out[(size_t)gr * NCLS + tx + 16] = l1 - lse;
        if (tx < 8) out[(size_t)gr * NCLS + tx + 32] = l2 - lse;
    }
}

extern "C" void kernel_launch(void* const* d_in, const int* in_sizes, int n_in,
                              void* d_out, int out_size, void* d_ws, size_t ws_size,
                              hipStream_t stream) {
    const float* x  = (const float*)d_in[0];
    const int* ei32 = (const int*)d_in[1];
    const float* W1 = (const float*)d_in[2];
    const float* as1 = (const float*)d_in[3];
    const float* ad1 = (const float*)d_in[4];
    const float* b1 = (const float*)d_in[5];
    const float* W2 = (const float*)d_in[6];
    const float* as2 = (const float*)d_in[7];
    const float* ad2 = (const float*)d_in[8];
    const float* b2 = (const float*)d_in[9];
    const float* W3 = (const float*)d_in[10];
    const float* as3 = (const float*)d_in[11];
    const float* ad3 = (const float*)d_in[12];
    const float* b3 = (const float*)d_in[13];
    const float* Wl = (const float*)d_in[14];
    const float* bl = (const float*)d_in[15];
    float* out = (float*)d_out;

    // workspace layout
    char* w = (char*)d_ws;
    unsigned short* projb = (unsigned short*)w;  w += (size_t)NN * HDIM * 2;
    unsigned short* featb = (unsigned short*)w;  w += (size_t)NN * HDIM * 2;
    unsigned short* xb    = (unsigned short*)w;  w += (size_t)NN * FIN * 2;
    unsigned short* Wt1b  = (unsigned short*)w;  w += (size_t)HDIM * FIN * 2;
    unsigned short* Wt2b  = (unsigned short*)w;  w += (size_t)HDIM * HDIM * 2;
    unsigned short* Wt3b  = (unsigned short*)w;  w += (size_t)HDIM * HDIM * 2;
    float* als  = (float*)w;  w += (size_t)NN * NHEAD * 4;
    float* ald  = (float*)w;  w += (size_t)NN * NHEAD * 4;
    int* deg    = (int*)w;    w += (size_t)NN * 4;
    int* incl   = (int*)w;    w += (size_t)NN * 4;
    int* bsum   = (int*)w;    w += 256 * 4;
    int* indptr = (int*)w;    w += (size_t)(NN + 1) * 4;
    int* cursor = (int*)w;    w += (size_t)NN * 4;
    int* esrc   = (int*)w;    w += (size_t)ET * 4;

    // ---- merged prep: conv + wconv3 + deg histogram (independent work, one dispatch) ----
    hipMemsetAsync(deg, 0, (size_t)NN * 4, stream);
    prep_kernel<<<NB_CONV + NB_WCONV + NB_EDGE, 256, 0, stream>>>(
        x, xb, W1, W2, W3, Wt1b, Wt2b, Wt3b, ei32, deg);

    // ---- CSR scan + fill ----
    scan1<<<NB_SCAN, 256, 0, stream>>>(deg, incl, bsum);
    scan2<<<1, 256, 0, stream>>>(bsum);
    scan3<<<NB_SCAN, 256, 0, stream>>>(incl, bsum, deg, indptr, cursor);
    fill_kernel<<<NB_EDGE, 256, 0, stream>>>(ei32, cursor, esrc);

    // XCD-swizzled 1D gemm grid: 391 row-panels padded to 392 (49 groups of 8) x 4 col-blocks
    int ggrid = 8 * 4 * (((NN + 127) / 128 + 7) / 8);   // 1568
    int agrid = (NN + 3) / 4;

    // ---- layer 1 ----
    gemm_mfma<<<ggrid, 256, 0, stream>>>(xb, Wt1b, projb, as1, ad1, als, ald, NN, FIN);
    agg_kernel<<<agrid, 256, 0, stream>>>(projb, als, ald, indptr, esrc, b1, featb);
    // ---- layer 2 ----
    gemm_mfma<<<ggrid, 256, 0, stream>>>(featb, Wt2b, projb, as2, ad2, als, ald, NN, HDIM);
    agg_kernel<<<agrid, 256, 0, stream>>>(projb, als, ald, indptr, esrc, b2, featb);
    // ---- layer 3 ----
    gemm_mfma<<<ggrid, 256, 0, stream>>>(featb, Wt3b, projb, as3, ad3, als, ald, NN, HDIM);
    agg_kernel<<<agrid, 256, 0, stream>>>(projb, als, ald, indptr, esrc, b3, featb);
    // ---- final linear + log_softmax (fused) ----
    final_kernel<<<(NN + 63) / 64, 256, 0, stream>>>(featb, Wl, bl, out);
}